// Round 4
// baseline (483.306 us; speedup 1.0000x reference)
//
#include <hip/hip_runtime.h>
#include <stdint.h>
#include <stddef.h>

// Problem constants
#define B_ 4
#define N_ 2048
#define C_ 768
#define H_ 12
#define M_ (B_ * N_)          // 8192 tokens
// SCALE = 64^-0.5 = 0.125, applied to q at projection time

typedef __attribute__((ext_vector_type(8))) short bf16x8_t;   // 8 bf16 = 4 VGPRs (MFMA A/B frag)
typedef __attribute__((ext_vector_type(4))) float f32x4_t;    // MFMA C/D frag

// round-half-up fp32->bf16 pair pack (2 adds + 1 v_perm)
__device__ __forceinline__ unsigned pack2_bf16(float f0, float f1) {
  unsigned u0 = __builtin_bit_cast(unsigned, f0) + 0x8000u;
  unsigned u1 = __builtin_bit_cast(unsigned, f1) + 0x8000u;
  return __builtin_amdgcn_perm(u1, u0, 0x07060302u);  // bytes [0,1]=u0.hi16,[2,3]=u1.hi16
}

// RNE fp32->bf16 (epilogue stores)
__device__ __forceinline__ short f2bf(float f) {
  unsigned u = __builtin_bit_cast(unsigned, f);
  u = (u + 0x7FFFu + ((u >> 16) & 1u)) >> 16;
  return (short)u;
}

// async global->LDS, 16B per lane. LDS dest = wave-uniform base + lane*16.
__device__ __forceinline__ void gload_lds16(const short* g, const short* l) {
  __builtin_amdgcn_global_load_lds(
      (const __attribute__((address_space(1))) void*)g,
      (__attribute__((address_space(3))) void*)l, 16, 0, 0);
}

// ---------------------------------------------------------------------------
// Kernel 0: fp32 -> bf16 conversion of all GEMM operands (memory-bound, ~127MB)
// ---------------------------------------------------------------------------
#define XV 1572864
#define WV 147456
__global__ __launch_bounds__(256) void cvt_all(
    const float* __restrict__ x, const float* __restrict__ kin, const float* __restrict__ vin,
    const float* __restrict__ wq, const float* __restrict__ wk, const float* __restrict__ wv,
    const float* __restrict__ wp,
    unsigned short* __restrict__ xb, unsigned short* __restrict__ kb, unsigned short* __restrict__ vb,
    unsigned short* __restrict__ wqb, unsigned short* __restrict__ wkb, unsigned short* __restrict__ wvb,
    unsigned short* __restrict__ wpb)
{
  int i = blockIdx.x * 256 + threadIdx.x;     // vec4 index
  const float* s; unsigned short* d; int off;
  if      (i < XV)            { s = x;   d = xb;  off = i; }
  else if (i < 2 * XV)        { s = kin; d = kb;  off = i - XV; }
  else if (i < 3 * XV)        { s = vin; d = vb;  off = i - 2 * XV; }
  else if (i < 3 * XV + WV)   { s = wq;  d = wqb; off = i - 3 * XV; }
  else if (i < 3 * XV + 2*WV) { s = wk;  d = wkb; off = i - 3 * XV - WV; }
  else if (i < 3 * XV + 3*WV) { s = wv;  d = wvb; off = i - 3 * XV - 2 * WV; }
  else                        { s = wp;  d = wpb; off = i - 3 * XV - 3 * WV; }
  float4 v = ((const float4*)s)[off];
  uint2 p;
  p.x = pack2_bf16(v.x, v.y);
  p.y = pack2_bf16(v.z, v.w);
  ((uint2*)d)[off] = p;
}

// ---------------------------------------------------------------------------
// Kernel 1: QKV projections, bf16 inputs.  y = A @ W^T.
// m97 structure: 128x128 tile, BK=64, 256 thr = 4 waves (2x2), 4x4 acc/wave.
// z=0: q*0.125 -> [B,H,N,D]; z=1: k -> [B,H,N,D];
// z=2: v -> [B,H,D,N] via LDS-transpose epilogue (coalesced 16B stores).
// ---------------------------------------------------------------------------
__global__ __launch_bounds__(256) void proj_qkv(
    const short* __restrict__ xb, const short* __restrict__ kb, const short* __restrict__ vb,
    const short* __restrict__ wqb, const short* __restrict__ wkb, const short* __restrict__ wvb,
    short* __restrict__ q_ws, short* __restrict__ k_ws, short* __restrict__ vt_ws)
{
  const int z = blockIdx.z;
  const short* A = (z == 0) ? xb : (z == 1) ? kb : vb;
  const short* W = (z == 0) ? wqb : (z == 1) ? wkb : wvb;
  const int m0 = blockIdx.x * 128;
  const int n0 = blockIdx.y * 128;

  __shared__ __align__(16) short smem[128 * 136];
  short* As = smem;
  short* Bs = smem + 128 * 64;

  const int t = threadIdx.x;
  const int w = t >> 6, L = t & 63, L15 = L & 15, quad = L >> 4;
  const int wm = w & 1, wn = w >> 1;

  f32x4_t acc[4][4] = {};

  const short* ga = A + (size_t)(m0 + w * 32 + (L >> 3)) * C_ + (L & 7) * 8;
  const short* gb = W + (size_t)(n0 + w * 32 + (L >> 3)) * C_ + (L & 7) * 8;
  const short* la = As + (w * 32) * 64;
  const short* lb = Bs + (w * 32) * 64;

  for (int k0 = 0; k0 < C_; k0 += 64) {
    __syncthreads();
    #pragma unroll
    for (int i = 0; i < 4; ++i) {
      gload_lds16(ga + (size_t)i * 8 * C_ + k0, la + i * 512);
      gload_lds16(gb + (size_t)i * 8 * C_ + k0, lb + i * 512);
    }
    __syncthreads();
    #pragma unroll
    for (int kk = 0; kk < 2; ++kk) {
      bf16x8_t af[4], bf[4];
      #pragma unroll
      for (int mt = 0; mt < 4; ++mt)
        af[mt] = *(const bf16x8_t*)&As[(wm * 64 + mt * 16 + L15) * 64 + kk * 32 + quad * 8];
      #pragma unroll
      for (int nt = 0; nt < 4; ++nt)
        bf[nt] = *(const bf16x8_t*)&Bs[(wn * 64 + nt * 16 + L15) * 64 + kk * 32 + quad * 8];
      #pragma unroll
      for (int mt = 0; mt < 4; ++mt)
        #pragma unroll
        for (int nt = 0; nt < 4; ++nt)
          acc[mt][nt] = __builtin_amdgcn_mfma_f32_16x16x32_bf16(af[mt], bf[nt], acc[mt][nt], 0, 0, 0);
    }
  }

  if (z != 2) {
    short* outp = (z == 0) ? q_ws : k_ws;
    const float mul = (z == 0) ? 0.125f : 1.0f;
    #pragma unroll
    for (int mt = 0; mt < 4; ++mt) {
      const int m_base = m0 + wm * 64 + mt * 16 + quad * 4;
      #pragma unroll
      for (int nt = 0; nt < 4; ++nt) {
        const int c = n0 + wn * 64 + nt * 16 + L15;
        const int h = c >> 6, d = c & 63;
        #pragma unroll
        for (int r = 0; r < 4; ++r) {
          const int m = m_base + r;
          const int b = m >> 11, n = m & 2047;
          outp[((size_t)(b * H_ + h) * N_ + n) * 64 + d] = f2bf(acc[mt][nt][r] * mul);
        }
      }
    }
  } else {
    // ---- transpose epilogue: acc -> LDS [c_local][m_local] -> coalesced v^T ----
    __syncthreads();   // main loop's last reads of As/Bs done
    #pragma unroll
    for (int mt = 0; mt < 4; ++mt) {
      const int ml = wm * 64 + mt * 16 + quad * 4;
      #pragma unroll
      for (int nt = 0; nt < 4; ++nt) {
        const int cl = wn * 64 + nt * 16 + L15;
        #pragma unroll
        for (int r = 0; r < 4; ++r)
          smem[cl * 136 + ml + r] = f2bf(acc[mt][nt][r]);
      }
    }
    __syncthreads();
    const int bb = m0 >> 11;          // 128-row tile never crosses a batch
    const int nn0 = m0 & 2047;
    #pragma unroll
    for (int pp = 0; pp < 8; ++pp) {
      const int cl = pp * 16 + (t >> 4);            // channel within tile
      const int mg = t & 15;                        // 8-token group
      const uint4 val = *(const uint4*)&smem[cl * 136 + mg * 8];
      const int cg = n0 + cl;
      *(uint4*)&vt_ws[(((size_t)(bb * H_ + (cg >> 6))) * 64 + (cg & 63)) * N_ + nn0 + mg * 8] = val;
    }
  }
}

// ---------------------------------------------------------------------------
// Kernel 2: fused attention.  One block = 128 q rows of one (b,h); 4 waves,
// each wave owns 32 q rows (2 m-tiles).  Q in registers.
// SWAPPED QK^T (T12 core): S^T = mfma(K_frag, Q_frag) -> each lane holds 4
// CONSECUTIVE kv of one q-row.  P writes become 8 x ds_write_b64 (was 32 x
// b16), bias loads become 8 x float4 (was 32 scalar), psum becomes 2 scalars.
// PV reads Ps in the same swizzled [q][kv] layout as before (unchanged).
// Async 2-phase DMA pipeline, one barrier/tile, source-swizzled staging,
// setprio around MFMA clusters — identical to the verified R3 structure.
// ---------------------------------------------------------------------------
__global__ __launch_bounds__(256, 3) void attn(
    const short* __restrict__ q_ws, const short* __restrict__ k_ws,
    const short* __restrict__ vt_ws, const float* __restrict__ rpb,
    short* __restrict__ attn_out)
{
  const int p  = blockIdx.x;
  const int lw = (p & 7) * 96 + (p >> 3);   // 768 = 8 XCDs x 96 contiguous
  const int h  = lw >> 6;                   // 64 x-slots per head
  const int xl = lw & 63;
  const int b  = xl & 3;
  const int m0 = (xl >> 2) * 128;
  const int bh = b * H_ + h;

  __shared__ __align__(16) short Ks [2][64 * 64];   // 2 x 8 KB, swizzled-by-source
  __shared__ __align__(16) short Vts[2][64 * 64];   // 2 x 8 KB (V^T tile)
  __shared__ __align__(16) short Ps [4][32 * 64];   // 16 KB, per-wave

  const int t = threadIdx.x;
  const int w = t >> 6, L = t & 63, L15 = L & 15, quad = L >> 4;

  const short* qp  = q_ws  + ((size_t)bh * N_ + m0) * 64;
  const short* kp  = k_ws  + (size_t)bh * N_ * 64;
  const short* vtp = vt_ws + (size_t)bh * 64 * N_;
  const float* bpb = rpb + (size_t)h * N_ * N_;

  // staging geometry: per wave, 2 gload_lds per operand fill 16 rows (8 rows/inst).
  // LDS linear dest; source col pre-swizzled ((L&7)^(L>>3))*16B == read-side XOR.
  const int srow8 = L >> 3;                      // 0..7
  const int scolS = ((L & 7) ^ srow8) * 8;       // swizzled source col (shorts)
  const short* gk_base = kp  + (size_t)(w * 16 + srow8) * 64 + scolS;
  const short* gv_base = vtp + (size_t)(w * 16 + srow8) * N_ + scolS;

  // Q fragments: loop-invariant -> registers.
  bf16x8_t aq[2][2];
  #pragma unroll
  for (int mt = 0; mt < 2; ++mt)
    #pragma unroll
    for (int kk = 0; kk < 2; ++kk)
      aq[mt][kk] = *(const bf16x8_t*)(qp + (size_t)(w * 32 + mt * 16 + L15) * 64 + kk * 32 + quad * 8);

  // bias base for SWAPPED layout: row = q (per-lane L15), col = 4 consecutive kv.
  const float* bq = bpb + (size_t)(m0 + w * 32 + L15) * N_ + quad * 4;

  f32x4_t o[2][4] = {};
  float psum[2] = {0.0f, 0.0f};
  f32x4_t bias[2][4];

  // ---- prologue: stage tile 0 into buffer 0, prefetch bias tile 0 ----
  #pragma unroll
  for (int i = 0; i < 2; ++i) {
    gload_lds16(gk_base + (size_t)i * 8 * 64, &Ks[0][w * 1024 + i * 512]);
    gload_lds16(gv_base + (size_t)i * 8 * N_, &Vts[0][w * 1024 + i * 512]);
  }
  #pragma unroll
  for (int mt = 0; mt < 2; ++mt)
    #pragma unroll
    for (int nt = 0; nt < 4; ++nt)
      bias[mt][nt] = *(const f32x4_t*)(bq + (size_t)mt * 16 * N_ + nt * 16);
  __syncthreads();   // drains vmcnt(0): tile 0 staged

  for (int T = 0; T < 32; ++T) {
    const int cur = T & 1, nxt = cur ^ 1;

    // ---- issue DMA for tile T+1 into the other buffer (in flight all tile) ----
    if (T < 31) {
      const int kv1 = (T + 1) * 64;
      #pragma unroll
      for (int i = 0; i < 2; ++i) {
        gload_lds16(gk_base + (size_t)(kv1 + i * 8) * 64, &Ks[nxt][w * 1024 + i * 512]);
        gload_lds16(gv_base + (size_t)i * 8 * N_ + kv1,   &Vts[nxt][w * 1024 + i * 512]);
      }
    }

    // ---- QK^T (swapped): S^T[kv][q], bias float4 as C-init ----
    f32x4_t s[2][4];
    __builtin_amdgcn_s_setprio(1);
    #pragma unroll
    for (int nt = 0; nt < 4; ++nt) {
      const int row = nt * 16 + L15;
      const char* kbp = (const char*)Ks[cur] + row * 128;
      const int sx = (row & 7) << 4;
      const bf16x8_t k0 = *(const bf16x8_t*)(kbp + ((quad * 16) ^ sx));
      const bf16x8_t k1 = *(const bf16x8_t*)(kbp + ((64 + quad * 16) ^ sx));
      #pragma unroll
      for (int mt = 0; mt < 2; ++mt) {
        f32x4_t sv = bias[mt][nt];
        sv = __builtin_amdgcn_mfma_f32_16x16x32_bf16(k0, aq[mt][0], sv, 0, 0, 0);
        s[mt][nt] = __builtin_amdgcn_mfma_f32_16x16x32_bf16(k1, aq[mt][1], sv, 0, 0, 0);
      }
    }
    __builtin_amdgcn_s_setprio(0);

    // ---- bias regs now dead: prefetch bias for tile T+1 (lands during PV) ----
    if (T < 31) {
      const float* bqn = bq + (size_t)(T + 1) * 64;
      #pragma unroll
      for (int mt = 0; mt < 2; ++mt)
        #pragma unroll
        for (int nt = 0; nt < 4; ++nt)
          bias[mt][nt] = *(const f32x4_t*)(bqn + (size_t)mt * 16 * N_ + nt * 16);
    }

    // ---- exp, packed P write (b64), scalar row-sum accumulation ----
    #pragma unroll
    for (int mt = 0; mt < 2; ++mt) {
      const int qrow = mt * 16 + L15;
      const int swz = (qrow & 7) << 4;
      #pragma unroll
      for (int nt = 0; nt < 4; ++nt) {
        const float e0 = __expf(s[mt][nt][0]);
        const float e1 = __expf(s[mt][nt][1]);
        const float e2 = __expf(s[mt][nt][2]);
        const float e3 = __expf(s[mt][nt][3]);
        psum[mt] += (e0 + e1) + (e2 + e3);
        uint2 pk;
        pk.x = pack2_bf16(e0, e1);
        pk.y = pack2_bf16(e2, e3);
        const int cb = (nt * 32 + quad * 8) ^ swz;
        *(uint2*)((char*)Ps[w] + qrow * 128 + cb) = pk;
      }
    }

    // ---- PV on buffer cur (unchanged layout) ----
    __builtin_amdgcn_s_setprio(1);
    #pragma unroll
    for (int kk = 0; kk < 2; ++kk) {
      bf16x8_t pa[2];
      #pragma unroll
      for (int mt = 0; mt < 2; ++mt) {
        const int row = mt * 16 + L15;
        pa[mt] = *(const bf16x8_t*)((char*)Ps[w] + row * 128 +
                                    ((kk * 64 + quad * 16) ^ ((row & 7) << 4)));
      }
      #pragma unroll
      for (int nt = 0; nt < 4; ++nt) {
        const int row = nt * 16 + L15;
        const bf16x8_t vbf = *(const bf16x8_t*)((char*)Vts[cur] + row * 128 +
                                                ((kk * 64 + quad * 16) ^ ((row & 7) << 4)));
        #pragma unroll
        for (int mt = 0; mt < 2; ++mt)
          o[mt][nt] = __builtin_amdgcn_mfma_f32_16x16x32_bf16(pa[mt], vbf, o[mt][nt], 0, 0, 0);
      }
    }
    __builtin_amdgcn_s_setprio(0);

    // ONE barrier per tile: implicit vmcnt(0) drain guarantees tile T+1 staged.
    __syncthreads();
  }

  // ---- denominator: sum quad-group partials, redistribute to O layout ----
  float inv[2];
  #pragma unroll
  for (int mt = 0; mt < 2; ++mt) {
    float v = psum[mt];
    v += __shfl_xor(v, 16);
    v += __shfl_xor(v, 32);
    inv[mt] = v;          // full sum for q = mt*16 + L15 (uniform across quads)
  }

  #pragma unroll
  for (int mt = 0; mt < 2; ++mt) {
    const int n_base = m0 + w * 32 + mt * 16 + quad * 4;
    float rl[4];
    #pragma unroll
    for (int r = 0; r < 4; ++r)
      rl[r] = 1.0f / __shfl(inv[mt], quad * 4 + r);   // lane L15'=quad*4+r holds it
    #pragma unroll
    for (int nt = 0; nt < 4; ++nt)
      #pragma unroll
      for (int r = 0; r < 4; ++r) {
        const float v = o[mt][nt][r] * rl[r];
        attn_out[((size_t)(b * N_ + n_base + r)) * C_ + h * 64 + nt * 16 + L15] = f2bf(v);
      }
  }
}

// ---------------------------------------------------------------------------
// Kernel 3: output projection.  out = attn_out(bf16) @ Wp^T + bp, fp32 out.
// ---------------------------------------------------------------------------
__global__ __launch_bounds__(256) void proj_out(
    const short* __restrict__ Abf, const short* __restrict__ wpb,
    const float* __restrict__ bpv, float* __restrict__ out)
{
  const int m0 = blockIdx.x * 128;
  const int n0 = blockIdx.y * 128;

  __shared__ short As[128 * 64];
  __shared__ short Bs[128 * 64];

  const int t = threadIdx.x;
  const int w = t >> 6, L = t & 63, L15 = L & 15, quad = L >> 4;
  const int wm = w & 1, wn = w >> 1;

  f32x4_t acc[4][4] = {};

  const short* ga = Abf + (size_t)(m0 + w * 32 + (L >> 3)) * C_ + (L & 7) * 8;
  const short* gb = wpb + (size_t)(n0 + w * 32 + (L >> 3)) * C_ + (L & 7) * 8;
  const short* la = &As[(w * 32) * 64];
  const short* lb = &Bs[(w * 32) * 64];

  for (int k0 = 0; k0 < C_; k0 += 64) {
    __syncthreads();
    #pragma unroll
    for (int i = 0; i < 4; ++i) {
      gload_lds16(ga + (size_t)i * 8 * C_ + k0, la + i * 512);
      gload_lds16(gb + (size_t)i * 8 * C_ + k0, lb + i * 512);
    }
    __syncthreads();
    #pragma unroll
    for (int kk = 0; kk < 2; ++kk) {
      bf16x8_t af[4], bf[4];
      #pragma unroll
      for (int mt = 0; mt < 4; ++mt)
        af[mt] = *(const bf16x8_t*)&As[(wm * 64 + mt * 16 + L15) * 64 + kk * 32 + quad * 8];
      #pragma unroll
      for (int nt = 0; nt < 4; ++nt)
        bf[nt] = *(const bf16x8_t*)&Bs[(wn * 64 + nt * 16 + L15) * 64 + kk * 32 + quad * 8];
      #pragma unroll
      for (int mt = 0; mt < 4; ++mt)
        #pragma unroll
        for (int nt = 0; nt < 4; ++nt)
          acc[mt][nt] = __builtin_amdgcn_mfma_f32_16x16x32_bf16(af[mt], bf[nt], acc[mt][nt], 0, 0, 0);
    }
  }

  #pragma unroll
  for (int mt = 0; mt < 4; ++mt) {
    const int m_base = m0 + wm * 64 + mt * 16 + quad * 4;
    #pragma unroll
    for (int nt = 0; nt < 4; ++nt) {
      const int c = n0 + wn * 64 + nt * 16 + L15;
      const float bb = bpv[c];
      #pragma unroll
      for (int r = 0; r < 4; ++r)
        out[(size_t)(m_base + r) * C_ + c] = acc[mt][nt][r] + bb;
    }
  }
}

// ---------------------------------------------------------------------------
extern "C" void kernel_launch(void* const* d_in, const int* in_sizes, int n_in,
                              void* d_out, int out_size, void* d_ws, size_t ws_size,
                              hipStream_t stream) {
  const float* x    = (const float*)d_in[0];
  const float* k_in = (const float*)d_in[1];
  const float* v_in = (const float*)d_in[2];
  const float* rpb  = (const float*)d_in[3];
  const float* Wq   = (const float*)d_in[4];
  const float* Wk   = (const float*)d_in[5];
  const float* Wv   = (const float*)d_in[6];
  const float* Wp   = (const float*)d_in[7];
  const float* bp   = (const float*)d_in[8];
  float* out = (float*)d_out;

  // workspace layout
  const size_t SZ = (size_t)B_ * H_ * N_ * 64 * sizeof(short);  // 12,582,912 B
  const size_t WSZ = (size_t)C_ * C_ * sizeof(short);           // 1,179,648 B
  char* ws = (char*)d_ws;
  short* q_ws  = (short*)(ws);
  short* k_ws  = (short*)(ws + SZ);
  short* vt_ws = (short*)(ws + 2 * SZ);
  short* ao_ws = (short*)(ws + 3 * SZ);
  short* xb    = (short*)(ws + 4 * SZ);
  short* kb    = (short*)(ws + 5 * SZ);
  short* vb    = (short*)(ws + 6 * SZ);
  short* wqb   = (short*)(ws + 7 * SZ);
  short* wkb   = (short*)(ws + 7 * SZ + WSZ);
  short* wvb   = (short*)(ws + 7 * SZ + 2 * WSZ);
  short* wpb   = (short*)(ws + 7 * SZ + 3 * WSZ);

  cvt_all<<<(3 * XV + 4 * WV + 255) / 256, 256, 0, stream>>>(
      x, k_in, v_in, Wq, Wk, Wv, Wp,
      (unsigned short*)xb, (unsigned short*)kb, (unsigned short*)vb,
      (unsigned short*)wqb, (unsigned short*)wkb, (unsigned short*)wvb, (unsigned short*)wpb);
  proj_qkv<<<dim3(M_ / 128, C_ / 128, 3), 256, 0, stream>>>(
      xb, kb, vb, wqb, wkb, wvb, q_ws, k_ws, vt_ws);
  attn<<<dim3(B_ * (N_ / 128) * H_), 256, 0, stream>>>(q_ws, k_ws, vt_ws, rpb, ao_ws);
  proj_out<<<dim3(M_ / 128, C_ / 128), 256, 0, stream>>>(ao_ws, wpb, bp, out);
}

// Round 5
// 456.966 us; speedup vs baseline: 1.0576x; 1.0576x over previous
//
#include <hip/hip_runtime.h>
#include <stdint.h>
#include <stddef.h>

// Problem constants
#define B_ 4
#define N_ 2048
#define C_ 768
#define H_ 12
#define M_ (B_ * N_)          // 8192 tokens
// SCALE = 64^-0.5 = 0.125, applied to q at projection time

typedef __attribute__((ext_vector_type(8))) short bf16x8_t;   // 8 bf16 = 4 VGPRs (MFMA A/B frag)
typedef __attribute__((ext_vector_type(4))) float f32x4_t;    // MFMA C/D frag

// round-half-up fp32->bf16 pair pack (2 adds + 1 v_perm)
__device__ __forceinline__ unsigned pack2_bf16(float f0, float f1) {
  unsigned u0 = __builtin_bit_cast(unsigned, f0) + 0x8000u;
  unsigned u1 = __builtin_bit_cast(unsigned, f1) + 0x8000u;
  return __builtin_amdgcn_perm(u1, u0, 0x07060302u);  // bytes [0,1]=u0.hi16,[2,3]=u1.hi16
}

// RNE fp32->bf16 (epilogue stores)
__device__ __forceinline__ short f2bf(float f) {
  unsigned u = __builtin_bit_cast(unsigned, f);
  u = (u + 0x7FFFu + ((u >> 16) & 1u)) >> 16;
  return (short)u;
}
// cheap half-up fp32->bf16 (hot P path)
__device__ __forceinline__ short f2bf_fast(float f) {
  return (short)((__builtin_bit_cast(unsigned, f) + 0x8000u) >> 16);
}

// async global->LDS, 16B per lane. LDS dest = wave-uniform base + lane*16.
__device__ __forceinline__ void gload_lds16(const short* g, const short* l) {
  __builtin_amdgcn_global_load_lds(
      (const __attribute__((address_space(1))) void*)g,
      (__attribute__((address_space(3))) void*)l, 16, 0, 0);
}

// ---------------------------------------------------------------------------
// Kernel 0: fp32 -> bf16 conversion of all GEMM operands (memory-bound, ~127MB)
// ---------------------------------------------------------------------------
#define XV 1572864
#define WV 147456
__global__ __launch_bounds__(256) void cvt_all(
    const float* __restrict__ x, const float* __restrict__ kin, const float* __restrict__ vin,
    const float* __restrict__ wq, const float* __restrict__ wk, const float* __restrict__ wv,
    const float* __restrict__ wp,
    unsigned short* __restrict__ xb, unsigned short* __restrict__ kb, unsigned short* __restrict__ vb,
    unsigned short* __restrict__ wqb, unsigned short* __restrict__ wkb, unsigned short* __restrict__ wvb,
    unsigned short* __restrict__ wpb)
{
  int i = blockIdx.x * 256 + threadIdx.x;     // vec4 index
  const float* s; unsigned short* d; int off;
  if      (i < XV)            { s = x;   d = xb;  off = i; }
  else if (i < 2 * XV)        { s = kin; d = kb;  off = i - XV; }
  else if (i < 3 * XV)        { s = vin; d = vb;  off = i - 2 * XV; }
  else if (i < 3 * XV + WV)   { s = wq;  d = wqb; off = i - 3 * XV; }
  else if (i < 3 * XV + 2*WV) { s = wk;  d = wkb; off = i - 3 * XV - WV; }
  else if (i < 3 * XV + 3*WV) { s = wv;  d = wvb; off = i - 3 * XV - 2 * WV; }
  else                        { s = wp;  d = wpb; off = i - 3 * XV - 3 * WV; }
  float4 v = ((const float4*)s)[off];
  uint2 p;
  p.x = pack2_bf16(v.x, v.y);
  p.y = pack2_bf16(v.z, v.w);
  ((uint2*)d)[off] = p;
}

// ---------------------------------------------------------------------------
// Kernel 1: QKV projections, bf16 inputs.  y = A @ W^T.
// 128x128 tile, BK=64, 4 waves (2x2), 4x4 acc/wave, global_load_lds staging.
// NEW: one-barrier DMA pipeline (same scheme as attn, verified R3): K-tile T+1
// DMA'd into the other LDS buffer while tile T computes; the end-of-step
// barrier's implicit vmcnt(0) drain is the only sync.  LDS 64KB -> 2 blk/CU.
// z=0: q*0.125 -> [B,H,N,D]; z=1: k -> [B,H,N,D];
// z=2: v -> [B,H,D,N] via LDS-transpose epilogue (coalesced 16B stores).
// ---------------------------------------------------------------------------
__global__ __launch_bounds__(256) void proj_qkv(
    const short* __restrict__ xb, const short* __restrict__ kb, const short* __restrict__ vb,
    const short* __restrict__ wqb, const short* __restrict__ wkb, const short* __restrict__ wvb,
    short* __restrict__ q_ws, short* __restrict__ k_ws, short* __restrict__ vt_ws)
{
  const int z = blockIdx.z;
  const short* A = (z == 0) ? xb : (z == 1) ? kb : vb;
  const short* W = (z == 0) ? wqb : (z == 1) ? wkb : wvb;
  const int m0 = blockIdx.x * 128;
  const int n0 = blockIdx.y * 128;

  // [buf][ A 128*64 | B 128*64 ] shorts; z=2 epilogue reuses front as 128x136.
  __shared__ __align__(16) short smem[2 * 16384];

  const int t = threadIdx.x;
  const int w = t >> 6, L = t & 63, L15 = L & 15, quad = L >> 4;
  const int wm = w & 1, wn = w >> 1;

  f32x4_t acc[4][4] = {};

  const short* ga = A + (size_t)(m0 + w * 32 + (L >> 3)) * C_ + (L & 7) * 8;
  const short* gb = W + (size_t)(n0 + w * 32 + (L >> 3)) * C_ + (L & 7) * 8;
  const int lofs = (w * 32) * 64;   // shorts, within a buffer half

  // ---- prologue: stage K-step 0 into buffer 0 ----
  #pragma unroll
  for (int i = 0; i < 4; ++i) {
    gload_lds16(ga + (size_t)i * 8 * C_, smem + lofs + i * 512);
    gload_lds16(gb + (size_t)i * 8 * C_, smem + 8192 + lofs + i * 512);
  }
  __syncthreads();

  for (int T = 0; T < 12; ++T) {
    const int cur = T & 1;
    const short* Acur = smem + cur * 16384;
    const short* Bcur = Acur + 8192;

    // issue DMA for K-step T+1 into the other buffer (in flight during MFMA)
    if (T < 11) {
      short* Anxt = smem + (cur ^ 1) * 16384;
      const int k1 = (T + 1) * 64;
      #pragma unroll
      for (int i = 0; i < 4; ++i) {
        gload_lds16(ga + (size_t)i * 8 * C_ + k1, Anxt + lofs + i * 512);
        gload_lds16(gb + (size_t)i * 8 * C_ + k1, Anxt + 8192 + lofs + i * 512);
      }
    }

    #pragma unroll
    for (int kk = 0; kk < 2; ++kk) {
      bf16x8_t af[4], bf[4];
      #pragma unroll
      for (int mt = 0; mt < 4; ++mt)
        af[mt] = *(const bf16x8_t*)&Acur[(wm * 64 + mt * 16 + L15) * 64 + kk * 32 + quad * 8];
      #pragma unroll
      for (int nt = 0; nt < 4; ++nt)
        bf[nt] = *(const bf16x8_t*)&Bcur[(wn * 64 + nt * 16 + L15) * 64 + kk * 32 + quad * 8];
      #pragma unroll
      for (int mt = 0; mt < 4; ++mt)
        #pragma unroll
        for (int nt = 0; nt < 4; ++nt)
          acc[mt][nt] = __builtin_amdgcn_mfma_f32_16x16x32_bf16(af[mt], bf[nt], acc[mt][nt], 0, 0, 0);
    }

    // one barrier per K-step: drains the DMA (next tile staged) and protects
    // buffer reuse (all waves done reading cur before it becomes the target).
    __syncthreads();
  }

  if (z != 2) {
    short* outp = (z == 0) ? q_ws : k_ws;
    const float mul = (z == 0) ? 0.125f : 1.0f;
    #pragma unroll
    for (int mt = 0; mt < 4; ++mt) {
      const int m_base = m0 + wm * 64 + mt * 16 + quad * 4;
      #pragma unroll
      for (int nt = 0; nt < 4; ++nt) {
        const int c = n0 + wn * 64 + nt * 16 + L15;
        const int h = c >> 6, d = c & 63;
        #pragma unroll
        for (int r = 0; r < 4; ++r) {
          const int m = m_base + r;
          const int b = m >> 11, n = m & 2047;
          outp[((size_t)(b * H_ + h) * N_ + n) * 64 + d] = f2bf(acc[mt][nt][r] * mul);
        }
      }
    }
  } else {
    // ---- transpose epilogue: acc -> LDS [c_local][m_local] -> coalesced v^T ----
    // (loop-end barrier already guarantees all LDS reads done)
    #pragma unroll
    for (int mt = 0; mt < 4; ++mt) {
      const int ml = wm * 64 + mt * 16 + quad * 4;
      #pragma unroll
      for (int nt = 0; nt < 4; ++nt) {
        const int cl = wn * 64 + nt * 16 + L15;
        #pragma unroll
        for (int r = 0; r < 4; ++r)
          smem[cl * 136 + ml + r] = f2bf(acc[mt][nt][r]);
      }
    }
    __syncthreads();
    const int bb = m0 >> 11;          // 128-row tile never crosses a batch
    const int nn0 = m0 & 2047;
    #pragma unroll
    for (int pp = 0; pp < 8; ++pp) {
      const int cl = pp * 16 + (t >> 4);            // channel within tile
      const int mg = t & 15;                        // 8-token group
      const uint4 val = *(const uint4*)&smem[cl * 136 + mg * 8];
      const int cg = n0 + cl;
      *(uint4*)&vt_ws[(((size_t)(bb * H_ + (cg >> 6))) * 64 + (cg & 63)) * N_ + nn0 + mg * 8] = val;
    }
  }
}

// ---------------------------------------------------------------------------
// Kernel 2: fused attention — exact R3 version (verified best: total 465.7).
// One block = 128 q rows of one (b,h); 4 waves, each owns 32 q rows.
// Q in registers; async 2-phase DMA pipeline; one barrier/tile;
// source-swizzled staging (T2 via m173); setprio around MFMA clusters.
// ---------------------------------------------------------------------------
__global__ __launch_bounds__(256, 3) void attn(
    const short* __restrict__ q_ws, const short* __restrict__ k_ws,
    const short* __restrict__ vt_ws, const float* __restrict__ rpb,
    short* __restrict__ attn_out)
{
  const int p  = blockIdx.x;
  const int lw = (p & 7) * 96 + (p >> 3);   // 768 = 8 XCDs x 96 contiguous
  const int h  = lw >> 6;                   // 64 x-slots per head
  const int xl = lw & 63;
  const int b  = xl & 3;
  const int m0 = (xl >> 2) * 128;
  const int bh = b * H_ + h;

  __shared__ __align__(16) short Ks [2][64 * 64];   // 2 x 8 KB, swizzled-by-source
  __shared__ __align__(16) short Vts[2][64 * 64];   // 2 x 8 KB (V^T tile)
  __shared__ __align__(16) short Ps [4][32 * 64];   // 16 KB, per-wave

  const int t = threadIdx.x;
  const int w = t >> 6, L = t & 63, L15 = L & 15, quad = L >> 4;

  const short* qp  = q_ws  + ((size_t)bh * N_ + m0) * 64;
  const short* kp  = k_ws  + (size_t)bh * N_ * 64;
  const short* vtp = vt_ws + (size_t)bh * 64 * N_;
  const float* bpb = rpb + (size_t)h * N_ * N_;

  // staging geometry: per wave, 2 gload_lds per operand fill 16 rows (8 rows/inst).
  // LDS linear dest; source col pre-swizzled ((L&7)^(L>>3))*16B == read-side XOR.
  const int srow8 = L >> 3;                      // 0..7
  const int scolS = ((L & 7) ^ srow8) * 8;       // swizzled source col (shorts)
  const short* gk_base = kp  + (size_t)(w * 16 + srow8) * 64 + scolS;
  const short* gv_base = vtp + (size_t)(w * 16 + srow8) * N_ + scolS;

  // Q fragments: loop-invariant -> registers.
  bf16x8_t aq[2][2];
  #pragma unroll
  for (int mt = 0; mt < 2; ++mt)
    #pragma unroll
    for (int kk = 0; kk < 2; ++kk)
      aq[mt][kk] = *(const bf16x8_t*)(qp + (size_t)(w * 32 + mt * 16 + L15) * 64 + kk * 32 + quad * 8);

  const float* bq = bpb + (size_t)(m0 + w * 32 + quad * 4) * N_ + L15;

  f32x4_t o[2][4] = {};
  float psum[2][4] = {};
  float bias[2][4][4];

  // ---- prologue: stage tile 0 into buffer 0, prefetch bias tile 0 ----
  #pragma unroll
  for (int i = 0; i < 2; ++i) {
    gload_lds16(gk_base + (size_t)i * 8 * 64, &Ks[0][w * 1024 + i * 512]);
    gload_lds16(gv_base + (size_t)i * 8 * N_, &Vts[0][w * 1024 + i * 512]);
  }
  #pragma unroll
  for (int mt = 0; mt < 2; ++mt)
    #pragma unroll
    for (int r = 0; r < 4; ++r)
      #pragma unroll
      for (int nt = 0; nt < 4; ++nt)
        bias[mt][nt][r] = bq[(size_t)(mt * 16 + r) * N_ + nt * 16];
  __syncthreads();   // drains vmcnt(0): tile 0 staged

  for (int T = 0; T < 32; ++T) {
    const int cur = T & 1, nxt = cur ^ 1;

    // ---- issue DMA for tile T+1 into the other buffer (in flight all tile) ----
    if (T < 31) {
      const int kv1 = (T + 1) * 64;
      #pragma unroll
      for (int i = 0; i < 2; ++i) {
        gload_lds16(gk_base + (size_t)(kv1 + i * 8) * 64, &Ks[nxt][w * 1024 + i * 512]);
        gload_lds16(gv_base + (size_t)i * 8 * N_ + kv1,   &Vts[nxt][w * 1024 + i * 512]);
      }
    }

    // ---- QK^T on buffer cur, bias (prefetched) as C-init ----
    f32x4_t s[2][4];
    __builtin_amdgcn_s_setprio(1);
    #pragma unroll
    for (int nt = 0; nt < 4; ++nt) {
      const int row = nt * 16 + L15;
      const char* kbp = (const char*)Ks[cur] + row * 128;
      const int sx = (row & 7) << 4;
      const bf16x8_t b0 = *(const bf16x8_t*)(kbp + ((quad * 16) ^ sx));
      const bf16x8_t b1 = *(const bf16x8_t*)(kbp + ((64 + quad * 16) ^ sx));
      #pragma unroll
      for (int mt = 0; mt < 2; ++mt) {
        f32x4_t sv = {bias[mt][nt][0], bias[mt][nt][1], bias[mt][nt][2], bias[mt][nt][3]};
        sv = __builtin_amdgcn_mfma_f32_16x16x32_bf16(aq[mt][0], b0, sv, 0, 0, 0);
        s[mt][nt] = __builtin_amdgcn_mfma_f32_16x16x32_bf16(aq[mt][1], b1, sv, 0, 0, 0);
      }
    }
    __builtin_amdgcn_s_setprio(0);

    // ---- bias regs now dead: prefetch bias for tile T+1 (lands during PV) ----
    if (T < 31) {
      const float* bqn = bq + (size_t)(T + 1) * 64;
      #pragma unroll
      for (int mt = 0; mt < 2; ++mt)
        #pragma unroll
        for (int r = 0; r < 4; ++r)
          #pragma unroll
          for (int nt = 0; nt < 4; ++nt)
            bias[mt][nt][r] = bqn[(size_t)(mt * 16 + r) * N_ + nt * 16];
    }

    // ---- exp, P write (swizzled), fp32 partial row-sums ----
    #pragma unroll
    for (int mt = 0; mt < 2; ++mt)
      #pragma unroll
      for (int nt = 0; nt < 4; ++nt)
        #pragma unroll
        for (int r = 0; r < 4; ++r) {
          const float e = __expf(s[mt][nt][r]);
          psum[mt][r] += e;
          const int qrow = mt * 16 + quad * 4 + r;
          const int cb = (nt * 32 + L15 * 2) ^ ((qrow & 7) << 4);
          *(short*)((char*)Ps[w] + qrow * 128 + cb) = f2bf_fast(e);
        }

    // ---- PV on buffer cur ----
    __builtin_amdgcn_s_setprio(1);
    #pragma unroll
    for (int kk = 0; kk < 2; ++kk) {
      bf16x8_t pa[2];
      #pragma unroll
      for (int mt = 0; mt < 2; ++mt) {
        const int row = mt * 16 + L15;
        pa[mt] = *(const bf16x8_t*)((char*)Ps[w] + row * 128 +
                                    ((kk * 64 + quad * 16) ^ ((row & 7) << 4)));
      }
      #pragma unroll
      for (int nt = 0; nt < 4; ++nt) {
        const int row = nt * 16 + L15;
        const bf16x8_t vbf = *(const bf16x8_t*)((char*)Vts[cur] + row * 128 +
                                                ((kk * 64 + quad * 16) ^ ((row & 7) << 4)));
        #pragma unroll
        for (int mt = 0; mt < 2; ++mt)
          o[mt][nt] = __builtin_amdgcn_mfma_f32_16x16x32_bf16(pa[mt], vbf, o[mt][nt], 0, 0, 0);
      }
    }
    __builtin_amdgcn_s_setprio(0);

    // ONE barrier per tile: implicit vmcnt(0) drain guarantees tile T+1 staged.
    __syncthreads();
  }

  // ---- denominator: reduce partials across the 16-lane L15 group, once ----
  #pragma unroll
  for (int mt = 0; mt < 2; ++mt)
    #pragma unroll
    for (int r = 0; r < 4; ++r) {
      float v = psum[mt][r];
      v += __shfl_xor(v, 1);
      v += __shfl_xor(v, 2);
      v += __shfl_xor(v, 4);
      v += __shfl_xor(v, 8);
      psum[mt][r] = 1.0f / v;
    }

  #pragma unroll
  for (int mt = 0; mt < 2; ++mt) {
    const int n_base = m0 + w * 32 + mt * 16 + quad * 4;
    #pragma unroll
    for (int nt = 0; nt < 4; ++nt)
      #pragma unroll
      for (int r = 0; r < 4; ++r) {
        const float v = o[mt][nt][r] * psum[mt][r];
        attn_out[((size_t)(b * N_ + n_base + r)) * C_ + h * 64 + nt * 16 + L15] = f2bf(v);
      }
  }
}

// ---------------------------------------------------------------------------
// Kernel 3: output projection.  out = attn_out(bf16) @ Wp^T + bp, fp32 out.
// Same one-barrier DMA pipeline as proj_qkv.
// ---------------------------------------------------------------------------
__global__ __launch_bounds__(256) void proj_out(
    const short* __restrict__ Abf, const short* __restrict__ wpb,
    const float* __restrict__ bpv, float* __restrict__ out)
{
  const int m0 = blockIdx.x * 128;
  const int n0 = blockIdx.y * 128;

  __shared__ __align__(16) short smem[2 * 16384];

  const int t = threadIdx.x;
  const int w = t >> 6, L = t & 63, L15 = L & 15, quad = L >> 4;
  const int wm = w & 1, wn = w >> 1;

  f32x4_t acc[4][4] = {};

  const short* ga = Abf + (size_t)(m0 + w * 32 + (L >> 3)) * C_ + (L & 7) * 8;
  const short* gb = wpb + (size_t)(n0 + w * 32 + (L >> 3)) * C_ + (L & 7) * 8;
  const int lofs = (w * 32) * 64;

  #pragma unroll
  for (int i = 0; i < 4; ++i) {
    gload_lds16(ga + (size_t)i * 8 * C_, smem + lofs + i * 512);
    gload_lds16(gb + (size_t)i * 8 * C_, smem + 8192 + lofs + i * 512);
  }
  __syncthreads();

  for (int T = 0; T < 12; ++T) {
    const int cur = T & 1;
    const short* Acur = smem + cur * 16384;
    const short* Bcur = Acur + 8192;

    if (T < 11) {
      short* Anxt = smem + (cur ^ 1) * 16384;
      const int k1 = (T + 1) * 64;
      #pragma unroll
      for (int i = 0; i < 4; ++i) {
        gload_lds16(ga + (size_t)i * 8 * C_ + k1, Anxt + lofs + i * 512);
        gload_lds16(gb + (size_t)i * 8 * C_ + k1, Anxt + 8192 + lofs + i * 512);
      }
    }

    #pragma unroll
    for (int kk = 0; kk < 2; ++kk) {
      bf16x8_t af[4], bf[4];
      #pragma unroll
      for (int mt = 0; mt < 4; ++mt)
        af[mt] = *(const bf16x8_t*)&Acur[(wm * 64 + mt * 16 + L15) * 64 + kk * 32 + quad * 8];
      #pragma unroll
      for (int nt = 0; nt < 4; ++nt)
        bf[nt] = *(const bf16x8_t*)&Bcur[(wn * 64 + nt * 16 + L15) * 64 + kk * 32 + quad * 8];
      #pragma unroll
      for (int mt = 0; mt < 4; ++mt)
        #pragma unroll
        for (int nt = 0; nt < 4; ++nt)
          acc[mt][nt] = __builtin_amdgcn_mfma_f32_16x16x32_bf16(af[mt], bf[nt], acc[mt][nt], 0, 0, 0);
    }

    __syncthreads();
  }

  #pragma unroll
  for (int mt = 0; mt < 4; ++mt) {
    const int m_base = m0 + wm * 64 + mt * 16 + quad * 4;
    #pragma unroll
    for (int nt = 0; nt < 4; ++nt) {
      const int c = n0 + wn * 64 + nt * 16 + L15;
      const float bb = bpv[c];
      #pragma unroll
      for (int r = 0; r < 4; ++r)
        out[(size_t)(m_base + r) * C_ + c] = acc[mt][nt][r] + bb;
    }
  }
}

// ---------------------------------------------------------------------------
extern "C" void kernel_launch(void* const* d_in, const int* in_sizes, int n_in,
                              void* d_out, int out_size, void* d_ws, size_t ws_size,
                              hipStream_t stream) {
  const float* x    = (const float*)d_in[0];
  const float* k_in = (const float*)d_in[1];
  const float* v_in = (const float*)d_in[2];
  const float* rpb  = (const float*)d_in[3];
  const float* Wq   = (const float*)d_in[4];
  const float* Wk   = (const float*)d_in[5];
  const float* Wv   = (const float*)d_in[6];
  const float* Wp   = (const float*)d_in[7];
  const float* bp   = (const float*)d_in[8];
  float* out = (float*)d_out;

  // workspace layout
  const size_t SZ = (size_t)B_ * H_ * N_ * 64 * sizeof(short);  // 12,582,912 B
  const size_t WSZ = (size_t)C_ * C_ * sizeof(short);           // 1,179,648 B
  char* ws = (char*)d_ws;
  short* q_ws  = (short*)(ws);
  short* k_ws  = (short*)(ws + SZ);
  short* vt_ws = (short*)(ws + 2 * SZ);
  short* ao_ws = (short*)(ws + 3 * SZ);
  short* xb    = (short*)(ws + 4 * SZ);
  short* kb    = (short*)(ws + 5 * SZ);
  short* vb    = (short*)(ws + 6 * SZ);
  short* wqb   = (short*)(ws + 7 * SZ);
  short* wkb   = (short*)(ws + 7 * SZ + WSZ);
  short* wvb   = (short*)(ws + 7 * SZ + 2 * WSZ);
  short* wpb   = (short*)(ws + 7 * SZ + 3 * WSZ);

  cvt_all<<<(3 * XV + 4 * WV + 255) / 256, 256, 0, stream>>>(
      x, k_in, v_in, Wq, Wk, Wv, Wp,
      (unsigned short*)xb, (unsigned short*)kb, (unsigned short*)vb,
      (unsigned short*)wqb, (unsigned short*)wkb, (unsigned short*)wvb, (unsigned short*)wpb);
  proj_qkv<<<dim3(M_ / 128, C_ / 128, 3), 256, 0, stream>>>(
      xb, kb, vb, wqb, wkb, wvb, q_ws, k_ws, vt_ws);
  attn<<<dim3(B_ * (N_ / 128) * H_), 256, 0, stream>>>(q_ws, k_ws, vt_ws, rpb, ao_ws);
  proj_out<<<dim3(M_ / 128, C_ / 128), 256, 0, stream>>>(ao_ws, wpb, bp, out);
}